// Round 8
// baseline (3425.563 us; speedup 1.0000x reference)
//
#include <hip/hip_runtime.h>

#define HDIM   256
#define NLAYER 10
#define BATCH  256
#define TSTEPS 512
#define NTHR   512
#define DEPTH  8
#define NCH    160               // chains = 10 layers x 16 slices
#define NWG    160

typedef __attribute__((ext_vector_type(8))) short short8;
typedef __attribute__((ext_vector_type(4))) float f32x4;

// ---------- bf16 helpers ----------
__device__ __forceinline__ unsigned short bf16_rne(float f) {
    unsigned v = __float_as_uint(f);
    unsigned r = v + 0x7FFFu + ((v >> 16) & 1u);
    return (unsigned short)(r >> 16);
}
__device__ __forceinline__ float bf16_f(unsigned short b) {
    return __uint_as_float(((unsigned)b) << 16);
}
__device__ __forceinline__ float fast_tanh(float v) {
    float a = fabsf(v);
    float e = __expf(-2.0f * a);
    float r = (1.0f - e) / (1.0f + e);
    return __builtin_copysignf(r, v);
}
__device__ __forceinline__ void cvt8(const float* __restrict__ p, short8& hi, short8& lo) {
#pragma unroll
    for (int e = 0; e < 8; ++e) {
        float f = p[e];
        unsigned short h = bf16_rne(f);
        hi[e] = (short)h;
        lo[e] = (short)bf16_rne(f - bf16_f(h));
    }
}
// 8 floats carried as 4 u64 -> hi/lo bf16 fragments
__device__ __forceinline__ void cvtq(unsigned long long q0, unsigned long long q1,
                                     unsigned long long q2, unsigned long long q3,
                                     short8& hi, short8& lo) {
    unsigned long long q[4] = { q0, q1, q2, q3 };
#pragma unroll
    for (int i = 0; i < 4; ++i) {
#pragma unroll
        for (int j = 0; j < 2; ++j) {
            const float f = __uint_as_float((unsigned)(q[i] >> (32 * j)));
            const unsigned short h = bf16_rne(f);
            hi[2 * i + j] = (short)h;
            lo[2 * i + j] = (short)bf16_rne(f - bf16_f(h));
        }
    }
}
// 4 u64 of packed (hi | lo<<16) -> hi/lo fragments
__device__ __forceinline__ void unpack8(unsigned long long q0, unsigned long long q1,
                                        unsigned long long q2, unsigned long long q3,
                                        short8& hi, short8& lo) {
    unsigned long long q[4] = { q0, q1, q2, q3 };
#pragma unroll
    for (int i = 0; i < 4; ++i) {
        unsigned u0 = (unsigned)q[i], u1 = (unsigned)(q[i] >> 32);
        hi[2 * i]     = (short)(u0 & 0xffffu); lo[2 * i]     = (short)(u0 >> 16);
        hi[2 * i + 1] = (short)(u1 & 0xffffu); lo[2 * i + 1] = (short)(u1 >> 16);
    }
}

#define MFMA16(a, b, c) __builtin_amdgcn_mfma_f32_16x16x32_bf16((a), (b), (c), 0, 0, 0)

__device__ __forceinline__ void wait_ge(int* f, int need) {
    while (__hip_atomic_load(f, __ATOMIC_RELAXED, __HIP_MEMORY_SCOPE_AGENT) < need)
        __builtin_amdgcn_s_sleep(1);
}
#define AT_LD(p)    __hip_atomic_load((p), __ATOMIC_RELAXED, __HIP_MEMORY_SCOPE_AGENT)
#define AT_ST(p, v) __hip_atomic_store((p), (v), __ATOMIC_RELAXED, __HIP_MEMORY_SCOPE_AGENT)
#define VMDRAIN()   asm volatile("s_waitcnt vmcnt(0)" ::: "memory")

// LDS byte layout (160 KB total):
#define WXH 0        // Wx_hi swizzled [c 256][k 256] bf16       : 131072
#define HHI 131072   // h(t-1) hi [row 16][k 256] bf16, swizzled :   8192
#define HLO 139264   // h(t-1) lo                                :   8192
#define XHI 147456   // x(t) hi                                  :   8192
#define XLO 155648   // x(t) lo                                  :   8192

// ---------- single cooperative kernel: merged feed+rec, deferred publish ----------
// launch_bounds (512, 1): only ever 1 wg/CU (160 wgs, 256 CUs) -> allow 256 VGPRs
// so the 192 weight registers are RESIDENT (r7's (512,2) capped at 128 -> spills).
__global__ void __launch_bounds__(NTHR, 1) rnn_fused(
    const int* __restrict__ tokens, const float* __restrict__ hidden0,
    const float* __restrict__ emb,
    const float* __restrict__ Wx_w, const float* __restrict__ Wx_b,
    const float* __restrict__ Wh_w, const float* __restrict__ Wh_b,
    unsigned* __restrict__ hg,        // [DEPTH][NCH][16*256] packed (hi | lo<<16)
    int* __restrict__ fh,             // [NCH][TSTEPS]
    float* __restrict__ out) {
    const int bid = blockIdx.x;
    const int l = bid >> 4;
    const int s16 = bid & 15;
    const int c = bid;
    const int tid = threadIdx.x;
    const int wv = tid >> 6;
    const int lane = tid & 63;
    const int ln15 = lane & 15;
    const int kq = (lane >> 4) << 3;      // k element sub-offset
    const int hi16 = (lane >> 4) << 4;    // k byte sub-offset
    const int swz = (ln15 & 7) << 4;
    const int srow = tid >> 5;            // staging row 0..15
    const int scb = tid & 31;             // staging 16B chunk 0..31

    __shared__ char smem[163840];
    float* hfinal = out + (size_t)BATCH * TSTEPS * HDIM;

    // ---- stage Wx_hi -> LDS (swizzled) ----
    {
        const float* wxsrcA = Wx_w + (size_t)l * 65536;
        for (int i = 0; i < 16; ++i) {
            const int ch = tid + i * NTHR;
            const int r = ch >> 5, kb = ch & 31;
            short8 hi, lo;
            cvt8(wxsrcA + (size_t)r * HDIM + kb * 8, hi, lo);
            *(short8*)(smem + WXH + r * 512 + ((kb * 16) ^ ((r & 7) << 4))) = hi;
        }
    }
    // ---- weight registers: Wh hi/lo + Wx lo, macro-unrolled literal indices + pin ----
    short8 whh[2][8], whl[2][8], wxl[2][8];
    {
        const float* whsrc = Wh_w + (size_t)l * 65536;
        const float* wxsrc = Wx_w + (size_t)l * 65536;
#define WINIT(ni, kc) do { \
        short8 _d; \
        cvt8(whsrc + (size_t)(wv * 32 + ni * 16 + ln15) * HDIM + kc * 32 + kq, whh[ni][kc], whl[ni][kc]); \
        cvt8(wxsrc + (size_t)(wv * 32 + ni * 16 + ln15) * HDIM + kc * 32 + kq, _d, wxl[ni][kc]); \
        asm volatile("" : "+v"(whh[ni][kc]), "+v"(whl[ni][kc]), "+v"(wxl[ni][kc])); \
    } while (0)
        WINIT(0,0); WINIT(0,1); WINIT(0,2); WINIT(0,3);
        WINIT(0,4); WINIT(0,5); WINIT(0,6); WINIT(0,7);
        WINIT(1,0); WINIT(1,1); WINIT(1,2); WINIT(1,3);
        WINIT(1,4); WINIT(1,5); WINIT(1,6); WINIT(1,7);
#undef WINIT
    }
    // ---- h(-1) = hidden0 slice -> LDS hi/lo (1 chunk per thread) ----
    {
        short8 hi, lo;
        cvt8(hidden0 + ((size_t)(l * BATCH + s16 * 16 + srow)) * HDIM + scb * 8, hi, lo);
        const int so = srow * 512 + ((scb * 16) ^ ((srow & 7) << 4));
        *(short8*)(smem + HHI + so) = hi;
        *(short8*)(smem + HLO + so) = lo;
    }
    // ---- bias ----
    float bv[2];
#pragma unroll
    for (int ni = 0; ni < 2; ++ni) {
        const int col = wv * 32 + ni * 16 + ln15;
        bv[ni] = Wx_b[l * HDIM + col] + Wh_b[l * HDIM + col];
    }

    int* fhme = fh + (size_t)c * TSTEPS;
    int* fhp = (l > 0) ? fh + (size_t)(c - 16) * TSTEPS : nullptr;
    int* fhn = (l < NLAYER - 1) ? fh + (size_t)(c + 16) * TSTEPS : nullptr;

    // ---- prologue: stage x(0) ----
    if (l > 0) {
        if (tid == 0) wait_ge(fhp + 0, 1);
        __syncthreads();
        unsigned long long* xp = (unsigned long long*)
            (hg + ((size_t)0 * NCH + (c - 16)) * 4096) + (size_t)tid * 4;
        unsigned long long q0 = AT_LD(xp), q1 = AT_LD(xp + 1),
                           q2 = AT_LD(xp + 2), q3 = AT_LD(xp + 3);
        short8 sxh, sxl;
        unpack8(q0, q1, q2, q3, sxh, sxl);
        const int so = srow * 512 + ((scb * 16) ^ ((srow & 7) << 4));
        *(short8*)(smem + XHI + so) = sxh;
        *(short8*)(smem + XLO + so) = sxl;
    } else {
        const int tok = tokens[(s16 * 16 + srow) * TSTEPS + 0];
        const float* ep = emb + (size_t)tok * HDIM + scb * 8;
        short8 sxh, sxl;
        cvt8(ep, sxh, sxl);
        const int so = srow * 512 + ((scb * 16) ^ ((srow & 7) << 4));
        *(short8*)(smem + XHI + so) = sxh;
        *(short8*)(smem + XLO + so) = sxl;
    }
    __syncthreads();   // all staging visible

    // ---- main loop ----
    // WAR proof: writer overwrites hg slot t%8 (h(t) over h(t-8)) in G of step t.
    // Consumer issued its loads of h(t-8) at A of its step t-9, drained them at its
    // mid-step VMDRAIN of step t-9, and its flag(t-9) (published in its G of step t-8,
    // after that drain + barrier) therefore attests the reads. Guard: wait fhn[t-9].
    for (int t = 0; t < TSTEPS; ++t) {
        // TOP: parallel polls, then one barrier
        if (tid == 0 && l > 0 && t + 1 < TSTEPS) wait_ge(fhp + (t + 1), 1);
        if (tid == 64 && fhn && t >= 9) wait_ge(fhn + (t - 9), 1);
        __syncthreads();

        // A: issue x(t+1) loads (held in regs until G)
        unsigned long long q0 = 0, q1 = 0, q2 = 0, q3 = 0;
        if (t + 1 < TSTEPS) {
            if (l > 0) {
                unsigned long long* xp = (unsigned long long*)
                    (hg + ((size_t)((t + 1) % DEPTH) * NCH + (c - 16)) * 4096) + (size_t)tid * 4;
                q0 = AT_LD(xp); q1 = AT_LD(xp + 1); q2 = AT_LD(xp + 2); q3 = AT_LD(xp + 3);
            } else {
                const int tok = tokens[(s16 * 16 + srow) * TSTEPS + (t + 1)];
                const unsigned long long* ep =
                    (const unsigned long long*)(emb + (size_t)tok * HDIM + scb * 8);
                q0 = ep[0]; q1 = ep[1]; q2 = ep[2]; q3 = ep[3];
            }
        }

        // B+C: acc = h(t-1)@Wh^T + x(t)@Wx^T   (12 MFMA per kc, macro-unrolled)
        f32x4 acc0 = {}, acc1 = {};
#define HX_KC(kc) do { \
        const int _off = ((kc) * 64 + hi16) ^ swz; \
        const short8 hh  = *(const short8*)(smem + HHI + ln15 * 512 + _off); \
        const short8 hl  = *(const short8*)(smem + HLO + ln15 * 512 + _off); \
        const short8 xh  = *(const short8*)(smem + XHI + ln15 * 512 + _off); \
        const short8 xl  = *(const short8*)(smem + XLO + ln15 * 512 + _off); \
        const short8 bh0 = *(const short8*)(smem + WXH + (wv * 32 + ln15) * 512 + _off); \
        const short8 bh1 = *(const short8*)(smem + WXH + (wv * 32 + 16 + ln15) * 512 + _off); \
        acc0 = MFMA16(hh, whh[0][kc], acc0);  acc1 = MFMA16(hh, whh[1][kc], acc1); \
        acc0 = MFMA16(hh, whl[0][kc], acc0);  acc1 = MFMA16(hh, whl[1][kc], acc1); \
        acc0 = MFMA16(hl, whh[0][kc], acc0);  acc1 = MFMA16(hl, whh[1][kc], acc1); \
        acc0 = MFMA16(xh, bh0, acc0);         acc1 = MFMA16(xh, bh1, acc1); \
        acc0 = MFMA16(xh, wxl[0][kc], acc0);  acc1 = MFMA16(xh, wxl[1][kc], acc1); \
        acc0 = MFMA16(xl, bh0, acc0);         acc1 = MFMA16(xl, bh1, acc1); \
    } while (0)
        HX_KC(0); HX_KC(1); HX_KC(2); HX_KC(3);
        HX_KC(4); HX_KC(5); HX_KC(6); HX_KC(7);
#undef HX_KC

        // D: tanh + pack (y reconstructed from hi+lo where needed)
        unsigned pk[2][4];
#pragma unroll
        for (int ni = 0; ni < 2; ++ni) {
            const f32x4 a = (ni == 0) ? acc0 : acc1;
#pragma unroll
            for (int r = 0; r < 4; ++r) {
                const float y = fast_tanh(a[r] + bv[ni]);
                const unsigned short yh = bf16_rne(y);
                const unsigned short yl = bf16_rne(y - bf16_f(yh));
                pk[ni][r] = (unsigned)yh | ((unsigned)yl << 16);
            }
        }

        VMDRAIN();          // x(t+1) loads arrived; h(t-1)/out stores (issued last step) done
        __syncthreads();    // all waves drained + all LDS reads of h(t-1), x(t) complete

        // G: publish flag(t-1); LDS writes h(t), x(t+1); issue global stores of h(t)
        if (tid == 0 && t > 0)
            AT_ST(fhme + (t - 1), 1);
        {
            unsigned* hgw = (fhn) ? hg + ((size_t)(t % DEPTH) * NCH + c) * 4096 : nullptr;
#pragma unroll
            for (int ni = 0; ni < 2; ++ni) {
                const int col = wv * 32 + ni * 16 + ln15;
#pragma unroll
                for (int r = 0; r < 4; ++r) {
                    const int row = ((lane >> 4) << 2) + r;
                    const int so = row * 512 + ((2 * col) ^ ((row & 7) << 4));
                    *(unsigned short*)(smem + HHI + so) = (unsigned short)(pk[ni][r] & 0xffffu);
                    *(unsigned short*)(smem + HLO + so) = (unsigned short)(pk[ni][r] >> 16);
                    if (hgw) {
                        AT_ST(hgw + (size_t)row * HDIM + col, pk[ni][r]);
                    } else {
                        const float y = bf16_f((unsigned short)(pk[ni][r] & 0xffffu)) +
                                        bf16_f((unsigned short)(pk[ni][r] >> 16));
                        out[((size_t)(s16 * 16 + row) * TSTEPS + t) * HDIM + col] = y;
                    }
                    if (t == TSTEPS - 1) {
                        const float y = bf16_f((unsigned short)(pk[ni][r] & 0xffffu)) +
                                        bf16_f((unsigned short)(pk[ni][r] >> 16));
                        hfinal[((size_t)l * BATCH + s16 * 16 + row) * HDIM + col] = y;
                    }
                }
            }
            if (t + 1 < TSTEPS) {
                short8 sxh, sxl;
                if (l > 0) unpack8(q0, q1, q2, q3, sxh, sxl);
                else       cvtq(q0, q1, q2, q3, sxh, sxl);
                const int so = srow * 512 + ((scb * 16) ^ ((srow & 7) << 4));
                *(short8*)(smem + XHI + so) = sxh;
                *(short8*)(smem + XLO + so) = sxl;
            }
        }
        // next iteration's TOP barrier separates these LDS writes from the next reads
    }
    // epilogue: final flag after draining the last hg stores
    VMDRAIN();
    __syncthreads();
    if (tid == 0) AT_ST(fhme + (TSTEPS - 1), 1);
}

// ---------- host ----------
extern "C" void kernel_launch(void* const* d_in, const int* in_sizes, int n_in,
                              void* d_out, int out_size, void* d_ws, size_t ws_size,
                              hipStream_t stream) {
    const int* tokens = (const int*)d_in[0];
    const float* hidden0 = (const float*)d_in[1];
    const float* emb = (const float*)d_in[2];
    const float* Wx_w = (const float*)d_in[3];
    const float* Wx_b = (const float*)d_in[4];
    const float* Wh_w = (const float*)d_in[5];
    const float* Wh_b = (const float*)d_in[6];
    float* out = (float*)d_out;

    char* ws = (char*)d_ws;
    size_t off = 0;
    auto carve = [&](size_t bytes) -> void* {
        void* p = ws + off;
        off = (off + bytes + 255) & ~(size_t)255;
        return p;
    };
    unsigned* hg = (unsigned*)carve((size_t)DEPTH * NCH * 16 * HDIM * 4);  // 21.0 MB
    int* fh = (int*)carve((size_t)NCH * TSTEPS * 4);                       // 0.33 MB
    (void)ws_size; (void)in_sizes; (void)n_in; (void)out_size;

    hipMemsetAsync(fh, 0, (size_t)NCH * TSTEPS * 4, stream);

    void* args[] = { (void*)&tokens, (void*)&hidden0, (void*)&emb,
                     (void*)&Wx_w, (void*)&Wx_b, (void*)&Wh_w, (void*)&Wh_b,
                     (void*)&hg, (void*)&fh, (void*)&out };
    hipLaunchCooperativeKernel((void*)rnn_fused, dim3(NWG), dim3(NTHR), args, 0, stream);
}

// Round 9
// 3407.169 us; speedup vs baseline: 1.0054x; 1.0054x over previous
//
#include <hip/hip_runtime.h>

#define HDIM   256
#define NLAYER 10
#define BATCH  256
#define TSTEPS 512
#define NTHR   512
#define DEPTH  8
#define NCH    160               // chains = 10 layers x 16 slices
#define NWG    160

typedef __attribute__((ext_vector_type(8))) short short8;
typedef __attribute__((ext_vector_type(4))) float f32x4;

// ---------- bf16 helpers ----------
__device__ __forceinline__ unsigned short bf16_rne(float f) {
    unsigned v = __float_as_uint(f);
    unsigned r = v + 0x7FFFu + ((v >> 16) & 1u);
    return (unsigned short)(r >> 16);
}
__device__ __forceinline__ float bf16_f(unsigned short b) {
    return __uint_as_float(((unsigned)b) << 16);
}
__device__ __forceinline__ float fast_tanh(float v) {
    float a = fabsf(v);
    float e = __expf(-2.0f * a);
    float r = (1.0f - e) / (1.0f + e);
    return __builtin_copysignf(r, v);
}
__device__ __forceinline__ void cvt8(const float* __restrict__ p, short8& hi, short8& lo) {
#pragma unroll
    for (int e = 0; e < 8; ++e) {
        float f = p[e];
        unsigned short h = bf16_rne(f);
        hi[e] = (short)h;
        lo[e] = (short)bf16_rne(f - bf16_f(h));
    }
}
// 8 floats carried as 4 u64 -> hi/lo bf16 fragments
__device__ __forceinline__ void cvtq(unsigned long long q0, unsigned long long q1,
                                     unsigned long long q2, unsigned long long q3,
                                     short8& hi, short8& lo) {
    unsigned long long q[4] = { q0, q1, q2, q3 };
#pragma unroll
    for (int i = 0; i < 4; ++i) {
#pragma unroll
        for (int j = 0; j < 2; ++j) {
            const float f = __uint_as_float((unsigned)(q[i] >> (32 * j)));
            const unsigned short h = bf16_rne(f);
            hi[2 * i + j] = (short)h;
            lo[2 * i + j] = (short)bf16_rne(f - bf16_f(h));
        }
    }
}
// 4 u64 of packed (hi | lo<<16) -> hi/lo fragments
__device__ __forceinline__ void unpack8(unsigned long long q0, unsigned long long q1,
                                        unsigned long long q2, unsigned long long q3,
                                        short8& hi, short8& lo) {
    unsigned long long q[4] = { q0, q1, q2, q3 };
#pragma unroll
    for (int i = 0; i < 4; ++i) {
        unsigned u0 = (unsigned)q[i], u1 = (unsigned)(q[i] >> 32);
        hi[2 * i]     = (short)(u0 & 0xffffu); lo[2 * i]     = (short)(u0 >> 16);
        hi[2 * i + 1] = (short)(u1 & 0xffffu); lo[2 * i + 1] = (short)(u1 >> 16);
    }
}

#define MFMA16(a, b, c) __builtin_amdgcn_mfma_f32_16x16x32_bf16((a), (b), (c), 0, 0, 0)

__device__ __forceinline__ void wait_ge(int* f, int need) {
    while (__hip_atomic_load(f, __ATOMIC_RELAXED, __HIP_MEMORY_SCOPE_AGENT) < need)
        __builtin_amdgcn_s_sleep(1);
}
#define AT_LD(p)    __hip_atomic_load((p), __ATOMIC_RELAXED, __HIP_MEMORY_SCOPE_AGENT)
#define AT_ST(p, v) __hip_atomic_store((p), (v), __ATOMIC_RELAXED, __HIP_MEMORY_SCOPE_AGENT)
#define VMDRAIN()   asm volatile("s_waitcnt vmcnt(0)" ::: "memory")

// LDS byte layout (160 KB total):
#define WXH 0        // Wx_hi swizzled [c 256][k 256] bf16       : 131072
#define HHI 131072   // h(t-1) hi [row 16][k 256] bf16, swizzled :   8192
#define HLO 139264   // h(t-1) lo                                :   8192
#define XHI 147456   // x(t) hi                                  :   8192
#define XLO 155648   // x(t) lo                                  :   8192

// ---------- single cooperative kernel: merged feed+rec, deferred publish ----------
// amdgpu_waves_per_eu(2,2): our block is 8 waves on 1 CU = exactly 2 waves/EU.
// Clamping the allocator to that occupancy raises the VGPR budget to 256 so the
// 192 weight registers are RESIDENT. (__launch_bounds__(512,1)'s 2nd arg is a
// min-waves hint that a 512-thread block already satisfies -> it did nothing,
// allocator targeted 4 waves/EU -> 128 VGPR cap -> weights spilled; r7/r8 evidence.)
__global__ void __launch_bounds__(NTHR)
__attribute__((amdgpu_waves_per_eu(2, 2))) rnn_fused(
    const int* __restrict__ tokens, const float* __restrict__ hidden0,
    const float* __restrict__ emb,
    const float* __restrict__ Wx_w, const float* __restrict__ Wx_b,
    const float* __restrict__ Wh_w, const float* __restrict__ Wh_b,
    unsigned* __restrict__ hg,        // [DEPTH][NCH][16*256] packed (hi | lo<<16)
    int* __restrict__ fh,             // [NCH][TSTEPS]
    float* __restrict__ out) {
    const int bid = blockIdx.x;
    const int l = bid >> 4;
    const int s16 = bid & 15;
    const int c = bid;
    const int tid = threadIdx.x;
    const int wv = tid >> 6;
    const int lane = tid & 63;
    const int ln15 = lane & 15;
    const int kq = (lane >> 4) << 3;      // k element sub-offset
    const int hi16 = (lane >> 4) << 4;    // k byte sub-offset
    const int swz = (ln15 & 7) << 4;
    const int srow = tid >> 5;            // staging row 0..15
    const int scb = tid & 31;             // staging 16B chunk 0..31

    __shared__ char smem[163840];
    float* hfinal = out + (size_t)BATCH * TSTEPS * HDIM;

    // ---- stage Wx_hi -> LDS (swizzled) ----
    {
        const float* wxsrcA = Wx_w + (size_t)l * 65536;
        for (int i = 0; i < 16; ++i) {
            const int ch = tid + i * NTHR;
            const int r = ch >> 5, kb = ch & 31;
            short8 hi, lo;
            cvt8(wxsrcA + (size_t)r * HDIM + kb * 8, hi, lo);
            *(short8*)(smem + WXH + r * 512 + ((kb * 16) ^ ((r & 7) << 4))) = hi;
        }
    }
    // ---- weight registers: Wh hi/lo + Wx lo, macro-unrolled literal indices + pin ----
    short8 whh[2][8], whl[2][8], wxl[2][8];
    {
        const float* whsrc = Wh_w + (size_t)l * 65536;
        const float* wxsrc = Wx_w + (size_t)l * 65536;
#define WINIT(ni, kc) do { \
        short8 _d; \
        cvt8(whsrc + (size_t)(wv * 32 + ni * 16 + ln15) * HDIM + kc * 32 + kq, whh[ni][kc], whl[ni][kc]); \
        cvt8(wxsrc + (size_t)(wv * 32 + ni * 16 + ln15) * HDIM + kc * 32 + kq, _d, wxl[ni][kc]); \
        asm volatile("" : "+v"(whh[ni][kc]), "+v"(whl[ni][kc]), "+v"(wxl[ni][kc])); \
    } while (0)
        WINIT(0,0); WINIT(0,1); WINIT(0,2); WINIT(0,3);
        WINIT(0,4); WINIT(0,5); WINIT(0,6); WINIT(0,7);
        WINIT(1,0); WINIT(1,1); WINIT(1,2); WINIT(1,3);
        WINIT(1,4); WINIT(1,5); WINIT(1,6); WINIT(1,7);
#undef WINIT
    }
    // ---- h(-1) = hidden0 slice -> LDS hi/lo (1 chunk per thread) ----
    {
        short8 hi, lo;
        cvt8(hidden0 + ((size_t)(l * BATCH + s16 * 16 + srow)) * HDIM + scb * 8, hi, lo);
        const int so = srow * 512 + ((scb * 16) ^ ((srow & 7) << 4));
        *(short8*)(smem + HHI + so) = hi;
        *(short8*)(smem + HLO + so) = lo;
    }
    // ---- bias ----
    float bv[2];
#pragma unroll
    for (int ni = 0; ni < 2; ++ni) {
        const int col = wv * 32 + ni * 16 + ln15;
        bv[ni] = Wx_b[l * HDIM + col] + Wh_b[l * HDIM + col];
    }

    int* fhme = fh + (size_t)c * TSTEPS;
    int* fhp = (l > 0) ? fh + (size_t)(c - 16) * TSTEPS : nullptr;
    int* fhn = (l < NLAYER - 1) ? fh + (size_t)(c + 16) * TSTEPS : nullptr;

    // ---- prologue: stage x(0) ----
    if (l > 0) {
        if (tid == 0) wait_ge(fhp + 0, 1);
        __syncthreads();
        unsigned long long* xp = (unsigned long long*)
            (hg + ((size_t)0 * NCH + (c - 16)) * 4096) + (size_t)tid * 4;
        unsigned long long q0 = AT_LD(xp), q1 = AT_LD(xp + 1),
                           q2 = AT_LD(xp + 2), q3 = AT_LD(xp + 3);
        short8 sxh, sxl;
        unpack8(q0, q1, q2, q3, sxh, sxl);
        const int so = srow * 512 + ((scb * 16) ^ ((srow & 7) << 4));
        *(short8*)(smem + XHI + so) = sxh;
        *(short8*)(smem + XLO + so) = sxl;
    } else {
        const int tok = tokens[(s16 * 16 + srow) * TSTEPS + 0];
        const float* ep = emb + (size_t)tok * HDIM + scb * 8;
        short8 sxh, sxl;
        cvt8(ep, sxh, sxl);
        const int so = srow * 512 + ((scb * 16) ^ ((srow & 7) << 4));
        *(short8*)(smem + XHI + so) = sxh;
        *(short8*)(smem + XLO + so) = sxl;
    }
    __syncthreads();   // all staging visible

    // ---- main loop ----
    // WAR proof: writer overwrites hg slot t%8 (h(t) over h(t-8)) in G of step t.
    // Consumer issued its loads of h(t-8) at A of its step t-9, drained them at its
    // mid-step VMDRAIN of step t-9, and its flag(t-9) (published in its G of step t-8,
    // after that drain + barrier) therefore attests the reads. Guard: wait fhn[t-9].
    for (int t = 0; t < TSTEPS; ++t) {
        // TOP: parallel polls, then one barrier
        if (tid == 0 && l > 0 && t + 1 < TSTEPS) wait_ge(fhp + (t + 1), 1);
        if (tid == 64 && fhn && t >= 9) wait_ge(fhn + (t - 9), 1);
        __syncthreads();

        // A: issue x(t+1) loads (held in regs until G)
        unsigned long long q0 = 0, q1 = 0, q2 = 0, q3 = 0;
        if (t + 1 < TSTEPS) {
            if (l > 0) {
                unsigned long long* xp = (unsigned long long*)
                    (hg + ((size_t)((t + 1) % DEPTH) * NCH + (c - 16)) * 4096) + (size_t)tid * 4;
                q0 = AT_LD(xp); q1 = AT_LD(xp + 1); q2 = AT_LD(xp + 2); q3 = AT_LD(xp + 3);
            } else {
                const int tok = tokens[(s16 * 16 + srow) * TSTEPS + (t + 1)];
                const unsigned long long* ep =
                    (const unsigned long long*)(emb + (size_t)tok * HDIM + scb * 8);
                q0 = ep[0]; q1 = ep[1]; q2 = ep[2]; q3 = ep[3];
            }
        }

        // B+C: acc = h(t-1)@Wh^T + x(t)@Wx^T   (12 MFMA per kc, macro-unrolled)
        f32x4 acc0 = {}, acc1 = {};
#define HX_KC(kc) do { \
        const int _off = ((kc) * 64 + hi16) ^ swz; \
        const short8 hh  = *(const short8*)(smem + HHI + ln15 * 512 + _off); \
        const short8 hl  = *(const short8*)(smem + HLO + ln15 * 512 + _off); \
        const short8 xh  = *(const short8*)(smem + XHI + ln15 * 512 + _off); \
        const short8 xl  = *(const short8*)(smem + XLO + ln15 * 512 + _off); \
        const short8 bh0 = *(const short8*)(smem + WXH + (wv * 32 + ln15) * 512 + _off); \
        const short8 bh1 = *(const short8*)(smem + WXH + (wv * 32 + 16 + ln15) * 512 + _off); \
        acc0 = MFMA16(hh, whh[0][kc], acc0);  acc1 = MFMA16(hh, whh[1][kc], acc1); \
        acc0 = MFMA16(hh, whl[0][kc], acc0);  acc1 = MFMA16(hh, whl[1][kc], acc1); \
        acc0 = MFMA16(hl, whh[0][kc], acc0);  acc1 = MFMA16(hl, whh[1][kc], acc1); \
        acc0 = MFMA16(xh, bh0, acc0);         acc1 = MFMA16(xh, bh1, acc1); \
        acc0 = MFMA16(xh, wxl[0][kc], acc0);  acc1 = MFMA16(xh, wxl[1][kc], acc1); \
        acc0 = MFMA16(xl, bh0, acc0);         acc1 = MFMA16(xl, bh1, acc1); \
    } while (0)
        HX_KC(0); HX_KC(1); HX_KC(2); HX_KC(3);
        HX_KC(4); HX_KC(5); HX_KC(6); HX_KC(7);
#undef HX_KC

        // D: tanh + pack (y reconstructed from hi+lo where needed)
        unsigned pk[2][4];
#pragma unroll
        for (int ni = 0; ni < 2; ++ni) {
            const f32x4 a = (ni == 0) ? acc0 : acc1;
#pragma unroll
            for (int r = 0; r < 4; ++r) {
                const float y = fast_tanh(a[r] + bv[ni]);
                const unsigned short yh = bf16_rne(y);
                const unsigned short yl = bf16_rne(y - bf16_f(yh));
                pk[ni][r] = (unsigned)yh | ((unsigned)yl << 16);
            }
        }

        VMDRAIN();          // x(t+1) loads arrived; h(t-1)/out stores (issued last step) done
        __syncthreads();    // all waves drained + all LDS reads of h(t-1), x(t) complete

        // G: publish flag(t-1); LDS writes h(t), x(t+1); issue global stores of h(t)
        if (tid == 0 && t > 0)
            AT_ST(fhme + (t - 1), 1);
        {
            unsigned* hgw = (fhn) ? hg + ((size_t)(t % DEPTH) * NCH + c) * 4096 : nullptr;
#pragma unroll
            for (int ni = 0; ni < 2; ++ni) {
                const int col = wv * 32 + ni * 16 + ln15;
#pragma unroll
                for (int r = 0; r < 4; ++r) {
                    const int row = ((lane >> 4) << 2) + r;
                    const int so = row * 512 + ((2 * col) ^ ((row & 7) << 4));
                    *(unsigned short*)(smem + HHI + so) = (unsigned short)(pk[ni][r] & 0xffffu);
                    *(unsigned short*)(smem + HLO + so) = (unsigned short)(pk[ni][r] >> 16);
                    if (hgw) {
                        AT_ST(hgw + (size_t)row * HDIM + col, pk[ni][r]);
                    } else {
                        const float y = bf16_f((unsigned short)(pk[ni][r] & 0xffffu)) +
                                        bf16_f((unsigned short)(pk[ni][r] >> 16));
                        out[((size_t)(s16 * 16 + row) * TSTEPS + t) * HDIM + col] = y;
                    }
                    if (t == TSTEPS - 1) {
                        const float y = bf16_f((unsigned short)(pk[ni][r] & 0xffffu)) +
                                        bf16_f((unsigned short)(pk[ni][r] >> 16));
                        hfinal[((size_t)l * BATCH + s16 * 16 + row) * HDIM + col] = y;
                    }
                }
            }
            if (t + 1 < TSTEPS) {
                short8 sxh, sxl;
                if (l > 0) unpack8(q0, q1, q2, q3, sxh, sxl);
                else       cvtq(q0, q1, q2, q3, sxh, sxl);
                const int so = srow * 512 + ((scb * 16) ^ ((srow & 7) << 4));
                *(short8*)(smem + XHI + so) = sxh;
                *(short8*)(smem + XLO + so) = sxl;
            }
        }
        // next iteration's TOP barrier separates these LDS writes from the next reads
    }
    // epilogue: final flag after draining the last hg stores
    VMDRAIN();
    __syncthreads();
    if (tid == 0) AT_ST(fhme + (TSTEPS - 1), 1);
}

// ---------- host ----------
extern "C" void kernel_launch(void* const* d_in, const int* in_sizes, int n_in,
                              void* d_out, int out_size, void* d_ws, size_t ws_size,
                              hipStream_t stream) {
    const int* tokens = (const int*)d_in[0];
    const float* hidden0 = (const float*)d_in[1];
    const float* emb = (const float*)d_in[2];
    const float* Wx_w = (const float*)d_in[3];
    const float* Wx_b = (const float*)d_in[4];
    const float* Wh_w = (const float*)d_in[5];
    const float* Wh_b = (const float*)d_in[6];
    float* out = (float*)d_out;

    char* ws = (char*)d_ws;
    size_t off = 0;
    auto carve = [&](size_t bytes) -> void* {
        void* p = ws + off;
        off = (off + bytes + 255) & ~(size_t)255;
        return p;
    };
    unsigned* hg = (unsigned*)carve((size_t)DEPTH * NCH * 16 * HDIM * 4);  // 21.0 MB
    int* fh = (int*)carve((size_t)NCH * TSTEPS * 4);                       // 0.33 MB
    (void)ws_size; (void)in_sizes; (void)n_in; (void)out_size;

    hipMemsetAsync(fh, 0, (size_t)NCH * TSTEPS * 4, stream);

    void* args[] = { (void*)&tokens, (void*)&hidden0, (void*)&emb,
                     (void*)&Wx_w, (void*)&Wx_b, (void*)&Wh_w, (void*)&Wh_b,
                     (void*)&hg, (void*)&fh, (void*)&out };
    hipLaunchCooperativeKernel((void*)rnn_fused, dim3(NWG), dim3(NTHR), args, 0, stream);
}

// Round 10
// 3372.172 us; speedup vs baseline: 1.0158x; 1.0104x over previous
//
#include <hip/hip_runtime.h>

#define HDIM   256
#define NLAYER 10
#define BATCH  256
#define TSTEPS 512
#define NTHR   512
#define DEPTH  8
#define NREC   160               // 10 layers x 16 slices (M=16 rows)
#define NFEED  16                // layer-0 u-producers, one per slice
#define NWG    176

typedef __attribute__((ext_vector_type(8))) short short8;
typedef __attribute__((ext_vector_type(4))) float f32x4;

// ---------- bf16 helpers ----------
__device__ __forceinline__ unsigned short bf16_rne(float f) {
    unsigned v = __float_as_uint(f);
    unsigned r = v + 0x7FFFu + ((v >> 16) & 1u);
    return (unsigned short)(r >> 16);
}
__device__ __forceinline__ float bf16_f(unsigned short b) {
    return __uint_as_float(((unsigned)b) << 16);
}
__device__ __forceinline__ float fast_tanh(float v) {
    float a = fabsf(v);
    float e = __expf(-2.0f * a);
    float r = (1.0f - e) / (1.0f + e);
    return __builtin_copysignf(r, v);
}
__device__ __forceinline__ void cvt8(const float* __restrict__ p, short8& hi, short8& lo) {
#pragma unroll
    for (int e = 0; e < 8; ++e) {
        float f = p[e];
        unsigned short h = bf16_rne(f);
        hi[e] = (short)h;
        lo[e] = (short)bf16_rne(f - bf16_f(h));
    }
}

#define MFMA16(a, b, c) __builtin_amdgcn_mfma_f32_16x16x32_bf16((a), (b), (c), 0, 0, 0)

__device__ __forceinline__ void wait_ge(int* f, int need) {
    while (__hip_atomic_load(f, __ATOMIC_RELAXED, __HIP_MEMORY_SCOPE_AGENT) < need)
        __builtin_amdgcn_s_sleep(1);
}
#define AT_LD(p)    __hip_atomic_load((p), __ATOMIC_RELAXED, __HIP_MEMORY_SCOPE_AGENT)
#define AT_ST(p, v) __hip_atomic_store((p), (v), __ATOMIC_RELAXED, __HIP_MEMORY_SCOPE_AGENT)
#define VMDRAIN()   asm volatile("s_waitcnt vmcnt(0)" ::: "memory")
#define PKF(a, b)   (((unsigned long long)__float_as_uint(b) << 32) | __float_as_uint(a))

// LDS byte layout (144 KB):
#define WXH 0        // Wx_{l+1} hi swizzled [c 256][k 256] bf16 : 131072
#define HHI 131072   // h(t-1) hi [row 16][k 256], swizzled      :   8192
#define HLO 139264   // h(t-1) lo                                :   8192

// stage 256x256 fp32 weight matrix -> LDS bf16-hi, XOR-swizzled
__device__ __forceinline__ void stage_whi_f32(const float* __restrict__ src, char* smem, int tid) {
    for (int i = 0; i < 16; ++i) {
        const int ch = tid + i * NTHR;
        const int r = ch >> 5, kb = ch & 31;
        short8 hi, lo;
        cvt8(src + (size_t)r * HDIM + kb * 8, hi, lo);
        *(short8*)(smem + r * 512 + ((kb * 16) ^ ((r & 7) << 4))) = hi;
    }
}

// ---------- single cooperative kernel: producer-computes-u pipeline ----------
// REC wg (l,s16): h_l(t) = tanh(u_l(t) + h_l(t-1)@Wh_l); also ships
// u_{l+1}(t-1) = h_l(t-1)@Wx_{l+1} + b_{l+1} computed from the SAME LDS A-frags.
// FEED wg (s16): u_0(t) = emb(tokens[:,t])@Wx_0 + b_0 (no recurrence, runs ahead).
//
// Flag/WAR lattice (all flags relaxed agent-scope; publishes follow a VMDRAIN+barrier):
//   fu[l][s][t]  : u_l(t) resident. REC l publishes fu_{l+1}[t-2] at G(t)
//                  (stores issued G(t-1), drained VMDRAIN(t)). FEED publishes fu_0[t]
//                  end-of-step t (drain inside step). Consumer waits fu_l[t] at TOP(t).
//   u-slot WAR   : REC l's store at G(t) hits slot (t-1)%8, overwriting u_{l+1}(t-9),
//                  read by wg_{l+1} at its step t-9 (drained at its VMDRAIN, attested by
//                  its own publish fu_{l+2}[t-11], or fd[t-9] for l==8). FEED stores slot
//                  t%8 overwriting u_0(t-8): attested by fu_1[t-10].
//   fd[s][t]     : wg_9 progress (published at G(t)), the WAR witness for wg_8.
// Epilogue (l<9): ship u_{l+1}(511) from h(511) (slot 7 WAR: fu_{l+2}[501] / fd[503]),
// then publish fu_{l+1}[510], [511].
__global__ void __launch_bounds__(NTHR) rnn_pipe(
    const int* __restrict__ tokens, const float* __restrict__ hidden0,
    const float* __restrict__ emb,
    const float* __restrict__ Wx_w, const float* __restrict__ Wx_b,
    const float* __restrict__ Wh_w, const float* __restrict__ Wh_b,
    float* __restrict__ u,            // [10 dl][16 s][DEPTH][4096] fp32, tid-linear frags
    int* __restrict__ fu,             // [10][16][TSTEPS]
    int* __restrict__ fd,             // [16][TSTEPS]
    float* __restrict__ out) {
    const int bid = blockIdx.x;
    const int tid = threadIdx.x;
    const int wv = tid >> 6;
    const int lane = tid & 63;
    const int ln15 = lane & 15;
    const int kq = (lane >> 4) << 3;
    const int hi16 = (lane >> 4) << 4;
    const int swz = (ln15 & 7) << 4;
    const int srow = tid >> 5;
    const int scb = tid & 31;

    __shared__ char smem[147456];
    float* hfinal = out + (size_t)BATCH * TSTEPS * HDIM;

    if (bid < NREC) {
        // ================= REC =================
        const int l = bid >> 4, s16 = bid & 15;
        const bool ship = (l < NLAYER - 1);

        if (ship) stage_whi_f32(Wx_w + (size_t)(l + 1) * 65536, smem, tid);
        // regs: Wh hi/lo (own layer) + Wx_{l+1} lo
        short8 whh[2][8], whl[2][8], wxl[2][8];
        {
            const float* whsrc = Wh_w + (size_t)l * 65536;
            const float* wxsrc = Wx_w + (size_t)(l + 1) * 65536;
#define WINIT(ni, kc) do { \
            cvt8(whsrc + (size_t)(wv * 32 + ni * 16 + ln15) * HDIM + kc * 32 + kq, whh[ni][kc], whl[ni][kc]); \
            if (ship) { short8 _d; \
                cvt8(wxsrc + (size_t)(wv * 32 + ni * 16 + ln15) * HDIM + kc * 32 + kq, _d, wxl[ni][kc]); } \
            else { wxl[ni][kc] = short8{0,0,0,0,0,0,0,0}; } \
            asm volatile("" : "+v"(whh[ni][kc]), "+v"(whl[ni][kc]), "+v"(wxl[ni][kc])); \
        } while (0)
            WINIT(0,0); WINIT(0,1); WINIT(0,2); WINIT(0,3);
            WINIT(0,4); WINIT(0,5); WINIT(0,6); WINIT(0,7);
            WINIT(1,0); WINIT(1,1); WINIT(1,2); WINIT(1,3);
            WINIT(1,4); WINIT(1,5); WINIT(1,6); WINIT(1,7);
#undef WINIT
        }
        // h(-1) -> LDS hi/lo (1 chunk per thread)
        {
            short8 hi, lo;
            cvt8(hidden0 + ((size_t)(l * BATCH + s16 * 16 + srow)) * HDIM + scb * 8, hi, lo);
            const int so = srow * 512 + ((scb * 16) ^ ((srow & 7) << 4));
            *(short8*)(smem + HHI + so) = hi;
            *(short8*)(smem + HLO + so) = lo;
        }
        // bias of the NEXT layer (folded into shipped u)
        float bvn[2] = { 0.f, 0.f };
        if (ship) {
#pragma unroll
            for (int ni = 0; ni < 2; ++ni) {
                const int col = wv * 32 + ni * 16 + ln15;
                bvn[ni] = Wx_b[(l + 1) * HDIM + col] + Wh_b[(l + 1) * HDIM + col];
            }
        }

        int* fuMe = fu + ((size_t)l * 16 + s16) * TSTEPS;
        int* fuNx = ship ? fu + ((size_t)(l + 1) * 16 + s16) * TSTEPS : nullptr;
        int* fuG  = (l < NLAYER - 2) ? fu + ((size_t)(l + 2) * 16 + s16) * TSTEPS : nullptr;
        int* fdA  = fd + (size_t)s16 * TSTEPS;
        const unsigned long long* myu = (const unsigned long long*)
            (u + ((size_t)l * 16 + s16) * DEPTH * 4096);
        unsigned long long* nxu = ship ? (unsigned long long*)
            (u + ((size_t)(l + 1) * 16 + s16) * DEPTH * 4096) : nullptr;

        __syncthreads();   // staging visible

        for (int t = 0; t < TSTEPS; ++t) {
            // TOP: parallel polls
            if (tid == 0) wait_ge(fuMe + t, 1);
            if (tid == 64 && ship) {
                if (l < NLAYER - 2) { if (t >= 11) wait_ge(fuG + (t - 11), 1); }
                else                { if (t >= 9)  wait_ge(fdA + (t - 9), 1); }
            }
            __syncthreads();

            // A: u_l(t) loads (tid-linear, 4x u64)
            const unsigned long long* up = myu + (size_t)(t & 7) * 2048 + (size_t)tid * 4;
            unsigned long long q0 = AT_LD(up), q1 = AT_LD(up + 1),
                               q2 = AT_LD(up + 2), q3 = AT_LD(up + 3);

            // B: acc_h = h(t-1)@Wh (4 chains); acc_u = h(t-1)@Wx_{l+1} (2 chains)
            const bool doU = ship && (t >= 1);
            f32x4 ah0a = {}, ah0b = {}, ah1a = {}, ah1b = {};
            f32x4 au0 = {}, au1 = {};
#define HX_KC(kc, A0, A1) do { \
            const int _off = ((kc) * 64 + hi16) ^ swz; \
            const short8 hh = *(const short8*)(smem + HHI + ln15 * 512 + _off); \
            const short8 hl = *(const short8*)(smem + HLO + ln15 * 512 + _off); \
            A0 = MFMA16(hh, whh[0][kc], A0);  A1 = MFMA16(hh, whh[1][kc], A1); \
            A0 = MFMA16(hh, whl[0][kc], A0);  A1 = MFMA16(hh, whl[1][kc], A1); \
            A0 = MFMA16(hl, whh[0][kc], A0);  A1 = MFMA16(hl, whh[1][kc], A1); \
            if (doU) { \
                const short8 bh0 = *(const short8*)(smem + WXH + (wv * 32 + ln15) * 512 + _off); \
                const short8 bh1 = *(const short8*)(smem + WXH + (wv * 32 + 16 + ln15) * 512 + _off); \
                au0 = MFMA16(hh, bh0, au0);         au1 = MFMA16(hh, bh1, au1); \
                au0 = MFMA16(hh, wxl[0][kc], au0);  au1 = MFMA16(hh, wxl[1][kc], au1); \
                au0 = MFMA16(hl, bh0, au0);         au1 = MFMA16(hl, bh1, au1); \
            } \
        } while (0)
            HX_KC(0, ah0a, ah1a); HX_KC(1, ah0a, ah1a);
            HX_KC(2, ah0a, ah1a); HX_KC(3, ah0a, ah1a);
            HX_KC(4, ah0b, ah1b); HX_KC(5, ah0b, ah1b);
            HX_KC(6, ah0b, ah1b); HX_KC(7, ah0b, ah1b);
#undef HX_KC

            VMDRAIN();          // u-loads arrived; prior u-stores done
            __syncthreads();    // all LDS reads of h(t-1) complete

            // G: publish fu_{l+1}[t-2]; h(t)=tanh(acc_h+u); LDS h; ship u(t-1); out
            if (tid == 0) {
                if (ship && t >= 2) AT_ST(fuNx + (t - 2), 1);
                if (!ship) AT_ST(fdA + t, 1);
            }
            unsigned pk[2][4];
            {
                const float uv[2][4] = {
                    { __uint_as_float((unsigned)q0), __uint_as_float((unsigned)(q0 >> 32)),
                      __uint_as_float((unsigned)q1), __uint_as_float((unsigned)(q1 >> 32)) },
                    { __uint_as_float((unsigned)q2), __uint_as_float((unsigned)(q2 >> 32)),
                      __uint_as_float((unsigned)q3), __uint_as_float((unsigned)(q3 >> 32)) } };
#pragma unroll
                for (int r = 0; r < 4; ++r) {
                    const float y0 = fast_tanh(ah0a[r] + ah0b[r] + uv[0][r]);
                    const float y1 = fast_tanh(ah1a[r] + ah1b[r] + uv[1][r]);
                    unsigned short h0 = bf16_rne(y0), h1 = bf16_rne(y1);
                    pk[0][r] = (unsigned)h0 | ((unsigned)bf16_rne(y0 - bf16_f(h0)) << 16);
                    pk[1][r] = (unsigned)h1 | ((unsigned)bf16_rne(y1 - bf16_f(h1)) << 16);
                }
            }
#pragma unroll
            for (int ni = 0; ni < 2; ++ni) {
                const int col = wv * 32 + ni * 16 + ln15;
#pragma unroll
                for (int r = 0; r < 4; ++r) {
                    const int row = ((lane >> 4) << 2) + r;
                    const int so = row * 512 + ((2 * col) ^ ((row & 7) << 4));
                    *(unsigned short*)(smem + HHI + so) = (unsigned short)(pk[ni][r] & 0xffffu);
                    *(unsigned short*)(smem + HLO + so) = (unsigned short)(pk[ni][r] >> 16);
                    if (!ship) {
                        const float y = bf16_f((unsigned short)(pk[ni][r] & 0xffffu)) +
                                        bf16_f((unsigned short)(pk[ni][r] >> 16));
                        out[((size_t)(s16 * 16 + row) * TSTEPS + t) * HDIM + col] = y;
                    }
                    if (t == TSTEPS - 1) {
                        const float y = bf16_f((unsigned short)(pk[ni][r] & 0xffffu)) +
                                        bf16_f((unsigned short)(pk[ni][r] >> 16));
                        hfinal[((size_t)l * BATCH + s16 * 16 + row) * HDIM + col] = y;
                    }
                }
            }
            if (doU) {
                unsigned long long* us = nxu + (size_t)((t - 1) & 7) * 2048 + (size_t)tid * 4;
                AT_ST(us + 0, PKF(au0[0] + bvn[0], au0[1] + bvn[0]));
                AT_ST(us + 1, PKF(au0[2] + bvn[0], au0[3] + bvn[0]));
                AT_ST(us + 2, PKF(au1[0] + bvn[1], au1[1] + bvn[1]));
                AT_ST(us + 3, PKF(au1[2] + bvn[1], au1[3] + bvn[1]));
            }
        }

        // ---- epilogue: ship u_{l+1}(511) from h(511) ----
        if (ship) {
            if (tid == 64) {
                if (l < NLAYER - 2) wait_ge(fuG + 501, 1);
                else                wait_ge(fdA + 503, 1);
            }
            __syncthreads();   // WAR + h(511) LDS visible
            f32x4 au0 = {}, au1 = {};
#define UE_KC(kc) do { \
            const int _off = ((kc) * 64 + hi16) ^ swz; \
            const short8 hh = *(const short8*)(smem + HHI + ln15 * 512 + _off); \
            const short8 hl = *(const short8*)(smem + HLO + ln15 * 512 + _off); \
            const short8 bh0 = *(const short8*)(smem + WXH + (wv * 32 + ln15) * 512 + _off); \
            const short8 bh1 = *(const short8*)(smem + WXH + (wv * 32 + 16 + ln15) * 512 + _off); \
            au0 = MFMA16(hh, bh0, au0);         au1 = MFMA16(hh, bh1, au1); \
            au0 = MFMA16(hh, wxl[0][kc], au0);  au1 = MFMA16(hh, wxl[1][kc], au1); \
            au0 = MFMA16(hl, bh0, au0);         au1 = MFMA16(hl, bh1, au1); \
        } while (0)
            UE_KC(0); UE_KC(1); UE_KC(2); UE_KC(3);
            UE_KC(4); UE_KC(5); UE_KC(6); UE_KC(7);
#undef UE_KC
            unsigned long long* us = nxu + (size_t)(511 & 7) * 2048 + (size_t)tid * 4;
            AT_ST(us + 0, PKF(au0[0] + bvn[0], au0[1] + bvn[0]));
            AT_ST(us + 1, PKF(au0[2] + bvn[0], au0[3] + bvn[0]));
            AT_ST(us + 2, PKF(au1[0] + bvn[1], au1[1] + bvn[1]));
            AT_ST(us + 3, PKF(au1[2] + bvn[1], au1[3] + bvn[1]));
            VMDRAIN();
            __syncthreads();
            if (tid == 0) {
                AT_ST(fuNx + 510, 1);
                AT_ST(fuNx + 511, 1);
            }
        }
    } else {
        // ================= FEED (layer 0 u-producer) =================
        const int s16 = bid - NREC;
        stage_whi_f32(Wx_w, smem, tid);
        short8 wxl[2][8];
#define FWINIT(ni, kc) do { \
        short8 _d; \
        cvt8(Wx_w + (size_t)(wv * 32 + ni * 16 + ln15) * HDIM + kc * 32 + kq, _d, wxl[ni][kc]); \
        asm volatile("" : "+v"(wxl[ni][kc])); \
    } while (0)
        FWINIT(0,0); FWINIT(0,1); FWINIT(0,2); FWINIT(0,3);
        FWINIT(0,4); FWINIT(0,5); FWINIT(0,6); FWINIT(0,7);
        FWINIT(1,0); FWINIT(1,1); FWINIT(1,2); FWINIT(1,3);
        FWINIT(1,4); FWINIT(1,5); FWINIT(1,6); FWINIT(1,7);
#undef FWINIT
        float b0[2];
#pragma unroll
        for (int ni = 0; ni < 2; ++ni) {
            const int col = wv * 32 + ni * 16 + ln15;
            b0[ni] = Wx_b[col] + Wh_b[col];
        }
        int* fuMe = fu + (size_t)s16 * TSTEPS;                    // dest layer 0
        int* fuG  = fu + ((size_t)16 + s16) * TSTEPS;             // layer-1 publishes = wg_0 progress
        unsigned long long* nxu = (unsigned long long*)
            (u + (size_t)s16 * DEPTH * 4096);
        __syncthreads();

        for (int t = 0; t < TSTEPS; ++t) {
            if (tid == 0 && t >= 10) wait_ge(fuG + (t - 10), 1);  // u_0 slot WAR
            __syncthreads();
            // stage emb rows -> LDS hi/lo (1 chunk/thread)
            {
                const int tok = tokens[(s16 * 16 + srow) * TSTEPS + t];
                short8 hi, lo;
                cvt8(emb + (size_t)tok * HDIM + scb * 8, hi, lo);
                const int so = srow * 512 + ((scb * 16) ^ ((srow & 7) << 4));
                *(short8*)(smem + HHI + so) = hi;
                *(short8*)(smem + HLO + so) = lo;
            }
            __syncthreads();
            f32x4 ax0 = {}, ax1 = {};
#define FX_KC(kc) do { \
            const int _off = ((kc) * 64 + hi16) ^ swz; \
            const short8 xh = *(const short8*)(smem + HHI + ln15 * 512 + _off); \
            const short8 xl = *(const short8*)(smem + HLO + ln15 * 512 + _off); \
            const short8 bh0 = *(const short8*)(smem + WXH + (wv * 32 + ln15) * 512 + _off); \
            const short8 bh1 = *(const short8*)(smem + WXH + (wv * 32 + 16 + ln15) * 512 + _off); \
            ax0 = MFMA16(xh, bh0, ax0);         ax1 = MFMA16(xh, bh1, ax1); \
            ax0 = MFMA16(xh, wxl[0][kc], ax0);  ax1 = MFMA16(xh, wxl[1][kc], ax1); \
            ax0 = MFMA16(xl, bh0, ax0);         ax1 = MFMA16(xl, bh1, ax1); \
        } while (0)
            FX_KC(0); FX_KC(1); FX_KC(2); FX_KC(3);
            FX_KC(4); FX_KC(5); FX_KC(6); FX_KC(7);
#undef FX_KC
            unsigned long long* us = nxu + (size_t)(t & 7) * 2048 + (size_t)tid * 4;
            AT_ST(us + 0, PKF(ax0[0] + b0[0], ax0[1] + b0[0]));
            AT_ST(us + 1, PKF(ax0[2] + b0[0], ax0[3] + b0[0]));
            AT_ST(us + 2, PKF(ax1[0] + b0[1], ax1[1] + b0[1]));
            AT_ST(us + 3, PKF(ax1[2] + b0[1], ax1[3] + b0[1]));
            VMDRAIN();
            __syncthreads();   // every wave's stores drained
            if (tid == 0) AT_ST(fuMe + t, 1);
        }
    }
}

// ---------- host ----------
extern "C" void kernel_launch(void* const* d_in, const int* in_sizes, int n_in,
                              void* d_out, int out_size, void* d_ws, size_t ws_size,
                              hipStream_t stream) {
    const int* tokens = (const int*)d_in[0];
    const float* hidden0 = (const float*)d_in[1];
    const float* emb = (const float*)d_in[2];
    const float* Wx_w = (const float*)d_in[3];
    const float* Wx_b = (const float*)d_in[4];
    const float* Wh_w = (const float*)d_in[5];
    const float* Wh_b = (const float*)d_in[6];
    float* out = (float*)d_out;

    char* ws = (char*)d_ws;
    size_t off = 0;
    auto carve = [&](size_t bytes) -> void* {
        void* p = ws + off;
        off = (off + bytes + 255) & ~(size_t)255;
        return p;
    };
    float* u = (float*)carve((size_t)NLAYER * 16 * DEPTH * 4096 * 4);  // 20.97 MB
    int* fu = (int*)carve((size_t)NLAYER * 16 * TSTEPS * 4);           // 327.7 KB
    int* fd = (int*)carve((size_t)16 * TSTEPS * 4);                    // 32.8 KB
    (void)ws_size; (void)in_sizes; (void)n_in; (void)out_size;

    hipMemsetAsync(fu, 0, (size_t)(NLAYER * 16 + 16) * TSTEPS * 4, stream);  // fu+fd contiguous

    void* args[] = { (void*)&tokens, (void*)&hidden0, (void*)&emb,
                     (void*)&Wx_w, (void*)&Wx_b, (void*)&Wh_w, (void*)&Wh_b,
                     (void*)&u, (void*)&fu, (void*)&fd, (void*)&out };
    hipLaunchCooperativeKernel((void*)rnn_pipe, dim3(NWG), dim3(NTHR), args, 0, stream);
}